// Round 4
// baseline (230.180 us; speedup 1.0000x reference)
//
#include <hip/hip_runtime.h>
#include <math.h>

// Problem constants (fixed by setup_inputs: B=8,T=4096,D=1024,A=32,S=16,ttl=64)
constexpr int kB = 8;
constexpr int kT = 4096;
constexpr int kD = 1024;
constexpr int kA = 32;
constexpr int kS = 16;
constexpr int kH = 256;            // max(ttl*4, S*4)
constexpr int kW = kH - kS + 1;    // 241
constexpr int kBA = kB * kA;       // 256 anchors
constexpr int kRB = 128;           // rows per S1 block
constexpr int kNJ = kT / kRB;      // 32 row-blocks per batch
constexpr int kMK = 3;             // a 256-row window spans at most 3 row-blocks
constexpr int NC = kD / 256;       // 4 chunks of 256 floats (64 lanes x float4)

constexpr int NT = 1024;           // 16 waves
constexpr int NW = NT / 64;

__device__ inline float wredsum(float v) {
#pragma unroll
    for (int m = 32; m >= 1; m >>= 1) v += __shfl_xor(v, m, 64);
    return v;
}
__device__ inline float wredmax(float v) {
#pragma unroll
    for (int m = 32; m >= 1; m >>= 1) v = fmaxf(v, __shfl_xor(v, m, 64));
    return v;
}

// _ALIAS table as a switch (tokens are < 64)
__device__ inline int alias_of(int t) {
    switch (t) {
        case 11: case 13: case 16: return 11;
        case 21: case 22: case 23: return 21;
        case 31: case 32: case 33: return 31;
        case 41: case 42: case 43: case 44: return 41;
        case 51: case 52: case 53: return 51;
        default: return -1;
    }
}

// ---------------------------------------------------------------------------
// S1: stream every hidden row EXACTLY ONCE. Block = (batch b, row-block j of
// 128 rows). For each anchor whose window intersects this row-block (avg ~3.2
// candidates), accumulate per-dim window sums and sum-of-sqrt-norms over the
// rows in the intersection; write dense partials [anchor][k][1024] where
// k = j - (start>>7) in [0, nk).  Per-(row,anchor) math is identical to the
// previous verified kernel (same lane-dim grouping, butterfly, sqrt).
// ---------------------------------------------------------------------------
__global__ __launch_bounds__(NT) void s1_kernel(
    const float* __restrict__ hidden,        // (B,T,D)
    const float* __restrict__ anchor_repr,   // (B,A,D)
    const int*   __restrict__ anchor_end,    // (B,A)
    float*       __restrict__ partial,       // [kBA][kMK][kD]
    float*       __restrict__ pshift)        // [kBA][kMK]
{
    __shared__ float lanc[8][kD];    // 32 KB staged candidate anchors
    __shared__ float comb[NW][kD];   // 64 KB per-wave vecsum combine buffer
    __shared__ float ssh[NW];

    const int id = blockIdx.x;
    const int b  = id & 7;           // batch == XCD (shared anchor table in L2)
    const int j  = id >> 3;          // row-block 0..31
    const int tid  = threadIdx.x;
    const int lane = tid & 63;
    const int wave = tid >> 6;
    const int g  = wave >> 3;        // wave-group 0/1 (candidates split across groups)
    const int ww = wave & 7;         // wave-in-group: rows ww, ww+8, ..., ww+120
    const int r0 = j * kRB;

    // candidate anchors: window [start, start+255] intersects [r0, r0+127]
    const int* ae = anchor_end + b * kA;
    unsigned mask = 0;
    for (int a = 0; a < kA; ++a) {
        int st = ae[a] + 1;
        if ((st >> 7) <= j && j <= ((st + kH - 1) >> 7)) mask |= 1u << a;
    }

    const float* hbase = hidden + ((size_t)(b * kT + r0)) * kD + 4 * lane;

    while (mask) {
        // ---- extract up to 8 slots (compile-time indexed arrays only) ----
        int aidx[8], stv[8];
        int npass = 0;
        unsigned rem = mask;
#pragma unroll
        for (int s = 0; s < 8; ++s) {
            if (rem) { aidx[s] = __ffs((int)rem) - 1; rem &= rem - 1u; ++npass; }
            else       aidx[s] = -1;
            stv[s] = (aidx[s] >= 0) ? (ae[aidx[s]] + 1) : 0x40000000; // sentinel
        }
        mask = rem;

        // ---- stage candidate anchors to LDS (1 float/thread/slot) ----
#pragma unroll
        for (int s = 0; s < 8; ++s)
            if (aidx[s] >= 0)
                lanc[s][tid] = anchor_repr[((size_t)(b * kA + aidx[s])) * kD + tid];
        __syncthreads();

        // my group's slot starts (slot = 2c+g), selected with static indices
        int stc[4];
#pragma unroll
        for (int c = 0; c < 4; ++c) stc[c] = g ? stv[2 * c + 1] : stv[2 * c];

        float4 vs[4][NC];
#pragma unroll
        for (int c = 0; c < 4; ++c)
#pragma unroll
            for (int ch = 0; ch < NC; ++ch) vs[c][ch] = make_float4(0.f, 0.f, 0.f, 0.f);
        float sacc[4] = {0.f, 0.f, 0.f, 0.f};

        for (int t = 0; t < kRB / 8; ++t) {
            const int lr = ww + 8 * t;
            const int r  = r0 + lr;
            const bool in0 = ((unsigned)(r - stc[0]) < (unsigned)kH);
            const bool in1 = ((unsigned)(r - stc[1]) < (unsigned)kH);
            const bool in2 = ((unsigned)(r - stc[2]) < (unsigned)kH);
            const bool in3 = ((unsigned)(r - stc[3]) < (unsigned)kH);
            if (!(in0 | in1 | in2 | in3)) continue;   // wave-uniform skip
            float4 x[NC];
#pragma unroll
            for (int ch = 0; ch < NC; ++ch)
                x[ch] = *(const float4*)(hbase + (size_t)lr * kD + 256 * ch);
            const bool inc[4] = {in0, in1, in2, in3};
#pragma unroll
            for (int c = 0; c < 4; ++c) {
                if (inc[c]) {                          // wave-uniform branch
                    const float* ap = &lanc[2 * c + g][4 * lane];
                    float acc = 0.f;
#pragma unroll
                    for (int ch = 0; ch < NC; ++ch) {
                        float4 a4 = *(const float4*)(ap + 256 * ch);
                        vs[c][ch].x += x[ch].x; vs[c][ch].y += x[ch].y;
                        vs[c][ch].z += x[ch].z; vs[c][ch].w += x[ch].w;
                        float d0 = x[ch].x - a4.x, d1 = x[ch].y - a4.y;
                        float d2 = x[ch].z - a4.z, d3 = x[ch].w - a4.w;
                        acc += d0*d0 + d1*d1 + d2*d2 + d3*d3;
                    }
#pragma unroll
                    for (int m = 32; m >= 1; m >>= 1) acc += __shfl_xor(acc, m, 64);
                    sacc[c] += sqrtf(acc);
                }
            }
        }

        // ---- flush: two slots per iteration (group0 -> 2c, group1 -> 2c+1) ----
#pragma unroll
        for (int c = 0; c < 4; ++c) {
            __syncthreads();   // protect comb/ssh reuse
#pragma unroll
            for (int ch = 0; ch < NC; ++ch)
                *(float4*)&comb[wave][256 * ch + 4 * lane] = vs[c][ch];
            if (lane == 0) ssh[wave] = sacc[c];
            __syncthreads();
            float s0 = 0.f, s1 = 0.f;
#pragma unroll
            for (int w = 0; w < 8; ++w) { s0 += comb[w][tid]; s1 += comb[8 + w][tid]; }
            if (2 * c < npass) {
                const int ba0 = b * kA + aidx[2 * c];
                const int k0  = j - (stv[2 * c] >> 7);
                partial[((size_t)(ba0 * kMK + k0) << 10) + tid] = s0;
            }
            if (2 * c + 1 < npass) {
                const int ba1 = b * kA + aidx[2 * c + 1];
                const int k1  = j - (stv[2 * c + 1] >> 7);
                partial[((size_t)(ba1 * kMK + k1) << 10) + tid] = s1;
            }
            if (tid == 0 && 2 * c < npass) {
                float t0 = 0.f;
                for (int w = 0; w < 8; ++w) t0 += ssh[w];
                pshift[(b * kA + aidx[2 * c]) * kMK + (j - (stv[2 * c] >> 7))] = t0;
            }
            if (tid == 64 && 2 * c + 1 < npass) {
                float t1 = 0.f;
                for (int w = 8; w < 16; ++w) t1 += ssh[w];
                pshift[(b * kA + aidx[2 * c + 1]) * kMK + (j - (stv[2 * c + 1] >> 7))] = t1;
            }
        }
        __syncthreads();   // lanc safe to restage for next pass
    }
}

// ---------------------------------------------------------------------------
// S2: per anchor, combine the <=3 partials (mean/cosine/shift), token stats,
// and the unchanged window phase.
// ---------------------------------------------------------------------------
__global__ __launch_bounds__(NT) void s2_kernel(
    const float* __restrict__ anchor_repr,
    const int*   __restrict__ input_ids,
    const int*   __restrict__ anchor_end,
    const float* __restrict__ partial,
    const float* __restrict__ pshift,
    float*       __restrict__ out)
{
    __shared__ int   sfut[kH];
    __shared__ int   sspan[kS];
    __shared__ float sposw[kS];
    __shared__ float sr1[NW], sr2[NW], sr3[NW], sr4[NW], sr5[NW];
    __shared__ float s_sim, s_shift, s_hidc, s_tokc;
    __shared__ int   s_root, s_has;
    __shared__ unsigned long long s_spanmask, s_amask, s_hmask;
    __shared__ float s_denom;

    const int ba   = blockIdx.x;
    const int b    = ba / kA;
    const int tid  = threadIdx.x;
    const int lane = tid & 63;
    const int wave = tid >> 6;

    const int e     = anchor_end[ba];
    const int start = e + 1;
    const int* ids  = input_ids + b * kT;
    const int anchor_tok = ids[e];

    if (tid < kH) sfut[tid] = ids[start + tid];
    if (tid < kS) {
        sspan[tid] = ids[e - kS + 1 + tid];
        // pos_w = linspace(1.0,0.4,16)/sum; sum = 11.2
        sposw[tid] = (1.0f - 0.04f * (float)tid) * (1.0f / 11.2f);
    }

    // ---- combine S1 partials; thread t owns dim t (NT == kD) ----
    const float* arow = anchor_repr + (size_t)ba * kD;
    const int nk = ((start + kH - 1) >> 7) - (start >> 7) + 1;   // 2 or 3
    float tot = 0.f;
    for (int k = 0; k < nk; ++k)
        tot += partial[((size_t)(ba * kMK + k) << 10) + tid];
    float m  = tot * (1.0f / kH);
    float av = arow[tid];
    float pm2  = m * m;
    float pdot = m * av;
    float pa2  = av * av;
    float peq  = (tid < kH && sfut[tid] == anchor_tok) ? 1.f : 0.f;  // own write
    pm2 = wredsum(pm2); pdot = wredsum(pdot); pa2 = wredsum(pa2); peq = wredsum(peq);
    if (lane == 0) { sr2[wave] = pm2; sr3[wave] = pdot; sr4[wave] = pa2; sr5[wave] = peq; }
    __syncthreads();

    if (tid == 0) {
        float m2 = 0.f, dt = 0.f, a2 = 0.f, eqc = 0.f;
        for (int w = 0; w < NW; ++w) { m2 += sr2[w]; dt += sr3[w]; a2 += sr4[w]; eqc += sr5[w]; }
        float shift = 0.f;
        for (int k = 0; k < nk; ++k) shift += pshift[ba * kMK + k];
        float nf = fmaxf(sqrtf(m2), 1e-8f);
        float nr = fmaxf(sqrtf(a2), 1e-8f);
        float sim = dt / (nr * nf);
        s_sim   = sim;
        s_shift = shift * (1.0f / kH);
        s_hidc  = fmaxf(0.f, (1.f - sim) * 0.5f);
        s_tokc  = 1.f - eqc * (1.0f / kH);
    }
    if (tid == 64) {   // span analysis on a different wave than tid==0
        unsigned long long spanmask = 0;
        for (int s = 0; s < kS; ++s) spanmask |= 1ull << sspan[s];
        int root = -1;
        for (int s = 0; s < kS; ++s) { int al = alias_of(sspan[s]); if (al >= 0) { root = al; break; } }
        if (root < 0) {
            int counts[kS], maxc = 0;
            for (int s = 0; s < kS; ++s) {
                int c = 0;
                for (int s2 = 0; s2 < kS; ++s2) c += (sspan[s2] == sspan[s]) ? 1 : 0;
                counts[s] = c; if (c > maxc) maxc = c;
            }
            int mode = 64;
            for (int s = 0; s < kS; ++s) if (counts[s] == maxc && sspan[s] < mode) mode = sspan[s];
            root = mode;
        }
        unsigned long long am = 0, hm = 0; int has = 0;
        switch (root) {  // am: tokens with alias==root; hm: _COMPAT[root] as bitmask
            case 11: am = (1ull<<11)|(1ull<<13)|(1ull<<16);            hm = am;                       has = 1; break;
            case 21: am = (1ull<<21)|(1ull<<22)|(1ull<<23);            hm = am|(1ull<<14)|(1ull<<15); has = 1; break;
            case 31: am = (1ull<<31)|(1ull<<32)|(1ull<<33);            hm = am|(1ull<<15);            has = 1; break;
            case 41: am = (1ull<<41)|(1ull<<42)|(1ull<<43)|(1ull<<44); hm = am;                       has = 1; break;
            case 51: am = (1ull<<51)|(1ull<<52)|(1ull<<53);            hm = am|(1ull<<15);            has = 1; break;
            default: break;
        }
        s_root = root; s_has = has; s_spanmask = spanmask; s_amask = am; s_hmask = hm;
        s_denom = (float)__popcll(spanmask);   // == first_f.sum()
    }
    __syncthreads();

    // ---------------- window phase (unchanged) ----------------
    const int root = s_root, has = s_has;
    const unsigned long long spanmask = s_spanmask, amask = s_amask, hmask = s_hmask;
    const float inv_denom = 1.0f / s_denom;

    float sims = -1e30f, rootpers = 0.f, regime = 0.f, simsum = 0.f, cnt = 0.f;
    if (tid < kW) {
        float wex = 0.f, wpos = 0.f, wrp = 0.f, wal = 0.f, whard = 0.f;
        unsigned long long wm = 0;
#pragma unroll
        for (int s = 0; s < kS; ++s) {
            int tok = sfut[tid + s];
            wm |= 1ull << tok;
            bool eq = (tok == sspan[s]);
            wex  += eq ? 1.f : 0.f;
            wpos += eq ? sposw[s] : 0.f;
            wrp  += (tok == root) ? 1.f : 0.f;
            wal  += ((amask >> tok) & 1ull) ? 1.f : 0.f;
            whard += ((hmask >> tok) & 1ull) ? 1.f : 0.f;
        }
        float exact  = wex * (1.f / kS);
        float overlap = (float)__popcll(wm & spanmask) * inv_denom;
        rootpers = wrp * (1.f / kS);
        float aliasc = wal * (1.f / kS);
        float hard   = whard * (1.f / kS);
        regime = has ? (0.55f*hard  + 0.2f*overlap + 0.15f*aliasc + 0.1f*rootpers)
                     : (0.45f*exact + 0.3f*overlap + 0.1f*aliasc  + 0.15f*rootpers);
        sims = 0.25f*exact + 0.15f*overlap + 0.35f*wpos + 0.25f*regime;
        simsum = sims;
        cnt = (sims >= 0.6f) ? 1.f : 0.f;
    }
    float rmax = wredmax(sims);
    float rsum = wredsum(simsum);
    float rrp  = wredsum(rootpers);
    float rreg = wredsum(regime);
    float rcnt = wredsum(cnt);
    if (lane == 0) { sr1[wave] = rmax; sr2[wave] = rsum; sr3[wave] = rrp; sr4[wave] = rreg; sr5[wave] = rcnt; }
    __syncthreads();

    if (tid == 0) {
        float best = -1e30f, ssum = 0.f, srp = 0.f, sreg = 0.f, scnt = 0.f;
        for (int w = 0; w < NW; ++w) {
            best = fmaxf(best, sr1[w]); ssum += sr2[w]; srp += sr3[w]; sreg += sr4[w]; scnt += sr5[w];
        }
        const float invW = 1.0f / (float)kW;
        float msims = ssum * invW, mrp = srp * invW, mrc = sreg * invW, dmass = scnt * invW;
        float dcoh      = 0.6f*msims + 0.25f*mrp + 0.15f*mrc;
        float pattern_c = 1.f - (0.6f*best + 0.2f*mrp + 0.2f*mrc);
        float contr     = 0.2f*s_hidc + 0.2f*s_tokc + 0.6f*pattern_c;
        contr = fminf(fmaxf(contr, 0.f), 1.f);
        const int n = kB * kA;
        out[0*n + ba] = contr;
        out[1*n + ba] = s_shift;
        out[2*n + ba] = s_sim;
        out[3*n + ba] = s_hidc;
        out[4*n + ba] = s_tokc;
        out[5*n + ba] = pattern_c;
        out[6*n + ba] = dmass;
        out[7*n + ba] = dcoh;
    }
}

// ---------------------------------------------------------------------------
// Fallback: previous verified single kernel (used only if ws too small).
// ---------------------------------------------------------------------------
__global__ __launch_bounds__(NT) void monitor_kernel(
    const float* __restrict__ hidden,
    const float* __restrict__ anchor_repr,
    const int*   __restrict__ input_ids,
    const int*   __restrict__ anchor_end,
    float*       __restrict__ out)
{
    __shared__ float smean[NW][kD];
    __shared__ int   sfut[kH];
    __shared__ int   sspan[kS];
    __shared__ float sposw[kS];
    __shared__ float sr1[NW], sr2[NW], sr3[NW], sr4[NW], sr5[NW];
    __shared__ float s_sim, s_shift, s_hidc, s_tokc;
    __shared__ int   s_root, s_has;
    __shared__ unsigned long long s_spanmask, s_amask, s_hmask;
    __shared__ float s_denom;

    const int id = blockIdx.x;
    const int ba = (id & 7) * 32 + (id >> 3);
    const int b  = ba / kA;
    const int tid  = threadIdx.x;
    const int lane = tid & 63;
    const int wave = tid >> 6;

    const int e     = anchor_end[ba];
    const int start = e + 1;
    const int* ids  = input_ids + b * kT;
    const int anchor_tok = ids[e];

    if (tid < kH) sfut[tid] = ids[start + tid];
    if (tid < kS) {
        sspan[tid] = ids[e - kS + 1 + tid];
        sposw[tid] = (1.0f - 0.04f * (float)tid) * (1.0f / 11.2f);
    }

    const float* arow = anchor_repr + (size_t)ba * kD;
    float4 anc[NC];
#pragma unroll
    for (int c = 0; c < NC; ++c) anc[c] = *(const float4*)(arow + 256 * c + 4 * lane);
    const float* hbase = hidden + ((size_t)b * kT + start) * kD + 4 * lane;

    float sum[NC][4];
#pragma unroll
    for (int c = 0; c < NC; ++c)
#pragma unroll
        for (int j = 0; j < 4; ++j) sum[c][j] = 0.f;

    float ss[kH / NW];
#pragma unroll
    for (int k = 0; k < kH / NW; ++k) ss[k] = 0.f;
#pragma unroll
    for (int k = 0; k < kH / NW; ++k) {
        const float* rp = hbase + (size_t)(wave + NW * k) * kD;
        float acc = 0.f;
#pragma unroll
        for (int c = 0; c < NC; ++c) {
            float4 x = *(const float4*)(rp + 256 * c);
            float4 a = anc[c];
            sum[c][0] += x.x; sum[c][1] += x.y; sum[c][2] += x.z; sum[c][3] += x.w;
            float d0 = x.x - a.x, d1 = x.y - a.y, d2 = x.z - a.z, d3 = x.w - a.w;
            acc += d0*d0 + d1*d1 + d2*d2 + d3*d3;
        }
        ss[k] = acc;
    }
#pragma unroll
    for (int m = 32; m >= 1; m >>= 1) {
#pragma unroll
        for (int k = 0; k < kH / NW; ++k) ss[k] += __shfl_xor(ss[k], m, 64);
    }
    float shift_acc = 0.f;
#pragma unroll
    for (int k = 0; k < kH / NW; ++k) shift_acc += sqrtf(ss[k]);

#pragma unroll
    for (int c = 0; c < NC; ++c)
        *(float4*)&smean[wave][256 * c + 4 * lane] =
            make_float4(sum[c][0], sum[c][1], sum[c][2], sum[c][3]);
    if (lane == 0) sr1[wave] = shift_acc;
    __syncthreads();

    float tot = 0.f;
#pragma unroll
    for (int w = 0; w < NW; ++w) tot += smean[w][tid];
    float m  = tot * (1.0f / kH);
    float av = arow[tid];
    float pm2  = m * m;
    float pdot = m * av;
    float pa2  = av * av;
    float peq  = (tid < kH && sfut[tid] == anchor_tok) ? 1.f : 0.f;
    pm2 = wredsum(pm2); pdot = wredsum(pdot); pa2 = wredsum(pa2); peq = wredsum(peq);
    if (lane == 0) { sr2[wave] = pm2; sr3[wave] = pdot; sr4[wave] = pa2; sr5[wave] = peq; }
    __syncthreads();

    if (tid == 0) {
        float shift = 0.f, m2 = 0.f, dt = 0.f, a2 = 0.f, eqc = 0.f;
        for (int w = 0; w < NW; ++w) {
            shift += sr1[w]; m2 += sr2[w]; dt += sr3[w]; a2 += sr4[w]; eqc += sr5[w];
        }
        float nf = fmaxf(sqrtf(m2), 1e-8f);
        float nr = fmaxf(sqrtf(a2), 1e-8f);
        float sim = dt / (nr * nf);
        s_sim   = sim;
        s_shift = shift * (1.0f / kH);
        s_hidc  = fmaxf(0.f, (1.f - sim) * 0.5f);
        s_tokc  = 1.f - eqc * (1.0f / kH);
    }
    if (tid == 64) {
        unsigned long long spanmask = 0;
        for (int s = 0; s < kS; ++s) spanmask |= 1ull << sspan[s];
        int root = -1;
        for (int s = 0; s < kS; ++s) { int al = alias_of(sspan[s]); if (al >= 0) { root = al; break; } }
        if (root < 0) {
            int counts[kS], maxc = 0;
            for (int s = 0; s < kS; ++s) {
                int c = 0;
                for (int s2 = 0; s2 < kS; ++s2) c += (sspan[s2] == sspan[s]) ? 1 : 0;
                counts[s] = c; if (c > maxc) maxc = c;
            }
            int mode = 64;
            for (int s = 0; s < kS; ++s) if (counts[s] == maxc && sspan[s] < mode) mode = sspan[s];
            root = mode;
        }
        unsigned long long am = 0, hm = 0; int has = 0;
        switch (root) {
            case 11: am = (1ull<<11)|(1ull<<13)|(1ull<<16);            hm = am;                       has = 1; break;
            case 21: am = (1ull<<21)|(1ull<<22)|(1ull<<23);            hm = am|(1ull<<14)|(1ull<<15); has = 1; break;
            case 31: am = (1ull<<31)|(1ull<<32)|(1ull<<33);            hm = am|(1ull<<15);            has = 1; break;
            case 41: am = (1ull<<41)|(1ull<<42)|(1ull<<43)|(1ull<<44); hm = am;                       has = 1; break;
            case 51: am = (1ull<<51)|(1ull<<52)|(1ull<<53);            hm = am|(1ull<<15);            has = 1; break;
            default: break;
        }
        s_root = root; s_has = has; s_spanmask = spanmask; s_amask = am; s_hmask = hm;
        s_denom = (float)__popcll(spanmask);
    }
    __syncthreads();

    const int root = s_root, has = s_has;
    const unsigned long long spanmask = s_spanmask, amask = s_amask, hmask = s_hmask;
    const float inv_denom = 1.0f / s_denom;

    float sims = -1e30f, rootpers = 0.f, regime = 0.f, simsum = 0.f, cnt = 0.f;
    if (tid < kW) {
        float wex = 0.f, wpos = 0.f, wrp = 0.f, wal = 0.f, whard = 0.f;
        unsigned long long wm = 0;
#pragma unroll
        for (int s = 0; s < kS; ++s) {
            int tok = sfut[tid + s];
            wm |= 1ull << tok;
            bool eq = (tok == sspan[s]);
            wex  += eq ? 1.f : 0.f;
            wpos += eq ? sposw[s] : 0.f;
            wrp  += (tok == root) ? 1.f : 0.f;
            wal  += ((amask >> tok) & 1ull) ? 1.f : 0.f;
            whard += ((hmask >> tok) & 1ull) ? 1.f : 0.f;
        }
        float exact  = wex * (1.f / kS);
        float overlap = (float)__popcll(wm & spanmask) * inv_denom;
        rootpers = wrp * (1.f / kS);
        float aliasc = wal * (1.f / kS);
        float hard   = whard * (1.f / kS);
        regime = has ? (0.55f*hard  + 0.2f*overlap + 0.15f*aliasc + 0.1f*rootpers)
                     : (0.45f*exact + 0.3f*overlap + 0.1f*aliasc  + 0.15f*rootpers);
        sims = 0.25f*exact + 0.15f*overlap + 0.35f*wpos + 0.25f*regime;
        simsum = sims;
        cnt = (sims >= 0.6f) ? 1.f : 0.f;
    }
    float rmax = wredmax(sims);
    float rsum = wredsum(simsum);
    float rrp  = wredsum(rootpers);
    float rreg = wredsum(regime);
    float rcnt = wredsum(cnt);
    if (lane == 0) { sr1[wave] = rmax; sr2[wave] = rsum; sr3[wave] = rrp; sr4[wave] = rreg; sr5[wave] = rcnt; }
    __syncthreads();

    if (tid == 0) {
        float best = -1e30f, ssum = 0.f, srp = 0.f, sreg = 0.f, scnt = 0.f;
        for (int w = 0; w < NW; ++w) {
            best = fmaxf(best, sr1[w]); ssum += sr2[w]; srp += sr3[w]; sreg += sr4[w]; scnt += sr5[w];
        }
        const float invW = 1.0f / (float)kW;
        float msims = ssum * invW, mrp = srp * invW, mrc = sreg * invW, dmass = scnt * invW;
        float dcoh      = 0.6f*msims + 0.25f*mrp + 0.15f*mrc;
        float pattern_c = 1.f - (0.6f*best + 0.2f*mrp + 0.2f*mrc);
        float contr     = 0.2f*s_hidc + 0.2f*s_tokc + 0.6f*pattern_c;
        contr = fminf(fmaxf(contr, 0.f), 1.f);
        const int n = kB * kA;
        out[0*n + ba] = contr;
        out[1*n + ba] = s_shift;
        out[2*n + ba] = s_sim;
        out[3*n + ba] = s_hidc;
        out[4*n + ba] = s_tokc;
        out[5*n + ba] = pattern_c;
        out[6*n + ba] = dmass;
        out[7*n + ba] = dcoh;
    }
}

extern "C" void kernel_launch(void* const* d_in, const int* in_sizes, int n_in,
                              void* d_out, int out_size, void* d_ws, size_t ws_size,
                              hipStream_t stream) {
    const float* hidden      = (const float*)d_in[0];
    const float* anchor_repr = (const float*)d_in[1];
    const int*   input_ids   = (const int*)d_in[2];
    const int*   anchor_end  = (const int*)d_in[3];
    float* out = (float*)d_out;

    const size_t n_partial = (size_t)kBA * kMK * kD;                 // 768K floats (3 MB)
    const size_t need      = (n_partial + kBA * kMK) * sizeof(float);

    if (d_ws != nullptr && ws_size >= need) {
        float* partial = (float*)d_ws;
        float* pshift  = partial + n_partial;
        hipLaunchKernelGGL(s1_kernel, dim3(kB * kNJ), dim3(NT), 0, stream,
                           hidden, anchor_repr, anchor_end, partial, pshift);
        hipLaunchKernelGGL(s2_kernel, dim3(kBA), dim3(NT), 0, stream,
                           anchor_repr, input_ids, anchor_end, partial, pshift, out);
    } else {
        hipLaunchKernelGGL(monitor_kernel, dim3(kBA), dim3(NT), 0, stream,
                           hidden, anchor_repr, input_ids, anchor_end, out);
    }
}